// Round 3
// baseline (6678.289 us; speedup 1.0000x reference)
//
#include <hip/hip_runtime.h>
#include <stdint.h>

#define T_STEPS 256
#define TC      64            // time chunk
#define NCHUNK  4
#define BATCH   64
#define ISZ     1024
#define HSZ     1024
#define GSZ     4096
#define NWG     128
#define BH      (BATCH * HSZ)
#define TBH     (T_STEPS * BATCH * HSZ)

typedef __attribute__((ext_vector_type(8))) _Float16 f16x8;
typedef __attribute__((ext_vector_type(4))) _Float16 f16x4;
typedef __attribute__((ext_vector_type(2))) _Float16 f16x2;
typedef __attribute__((ext_vector_type(4))) float f32x4;

typedef __attribute__((address_space(1))) const void gas_void;
typedef __attribute__((address_space(3))) void las_void;

__device__ __forceinline__ void gload_lds16(const void* g, void* l) {
  __builtin_amdgcn_global_load_lds((gas_void*)g, (las_void*)l, 16, 0, 0);
}

__device__ __forceinline__ float sigf(float x) {
  return 1.0f / (1.0f + expf(-x));
}

// ---------------- fp32 -> f16 hi/lo split (lo scaled by 2048) ----------------
__global__ void k_split(const float* __restrict__ src, _Float16* __restrict__ hi,
                        _Float16* __restrict__ lo, int n4) {
  int i = blockIdx.x * blockDim.x + threadIdx.x;
  int st = gridDim.x * blockDim.x;
  for (; i < n4; i += st) {
    float4 v = ((const float4*)src)[i];
    f16x4 h, l;
#pragma unroll
    for (int e = 0; e < 4; ++e) {
      float x = ((const float*)&v)[e];
      _Float16 hh = (_Float16)x;
      float r = x - (float)hh;          // exact
      h[e] = hh;
      l[e] = (_Float16)(r * 2048.0f);   // scaled residual, stays normal
    }
    ((f16x4*)hi)[i] = h;
    ((f16x4*)lo)[i] = l;
  }
}

// ---------------- init: bias sum, h0 split, barrier ----------------
__global__ void k_init(const float* __restrict__ b_ih, const float* __restrict__ b_hh,
                       const int* __restrict__ bias_flag, const float* __restrict__ hidden,
                       float* __restrict__ bsum, _Float16* __restrict__ hhi,
                       _Float16* __restrict__ hlo, unsigned int* __restrict__ bar) {
  int i = blockIdx.x * blockDim.x + threadIdx.x;
  int st = gridDim.x * blockDim.x;
  int bias = bias_flag[0];
  for (int j = i; j < GSZ; j += st) bsum[j] = bias ? (b_ih[j] + b_hh[j]) : 0.f;
  for (int j = i; j < BH; j += st) {
    float x = hidden[j];
    _Float16 hh = (_Float16)x;
    hhi[j] = hh;
    hlo[j] = (_Float16)((x - (float)hh) * 2048.0f);
  }
  if (i < 8) bar[i] = 0u;
}

// ---------------- Gx = X @ w_ih^T, split-f16 3-pass, fp32 out ----------------
// tile 128(M) x 64(N), BK=32, double-buffered global_load_lds staging.
__global__ __launch_bounds__(256, 2) void k_gemm_gx(
    const _Float16* __restrict__ Ah, const _Float16* __restrict__ Al,
    const _Float16* __restrict__ Bh, const _Float16* __restrict__ Bl,
    float* __restrict__ C, int m_base) {
  __shared__ char smem[49152];  // 2 sets x (Ahi 8K | Alo 8K | Bhi 4K | Blo 4K)
  const int tid = threadIdx.x, lane = tid & 63, w = tid >> 6;
  const int m0 = blockIdx.y * 128, n0 = blockIdx.x * 64;
  const int wm = (w >> 1) * 64, wn = (w & 1) * 32;

  f32x4 ach[4][2], acl[4][2];
#pragma unroll
  for (int a = 0; a < 4; ++a)
#pragma unroll
    for (int b = 0; b < 2; ++b) {
      ach[a][b] = (f32x4){0.f, 0.f, 0.f, 0.f};
      acl[a][b] = (f32x4){0.f, 0.f, 0.f, 0.f};
    }

  auto stage = [&](int buf, int kk) {
    char* S = smem + buf * 24576;
    const int ke = kk * 32;
#pragma unroll
    for (int i = 0; i < 6; ++i) {
      int c = i * 256 + tid;   // [0,1536) chunks of 16B; regions align to 256
      if (c < 512) {           // Ahi: 128 rows x 4 chunks
        int row = c >> 2, kc = (c & 3) * 8;
        gload_lds16(Ah + (size_t)(m_base + m0 + row) * ISZ + ke + kc, S + c * 16);
      } else if (c < 1024) {   // Alo
        int c2 = c - 512; int row = c2 >> 2, kc = (c2 & 3) * 8;
        gload_lds16(Al + (size_t)(m_base + m0 + row) * ISZ + ke + kc, S + 8192 + c2 * 16);
      } else if (c < 1280) {   // Bhi: 64 rows x 4 chunks
        int c2 = c - 1024; int row = c2 >> 2, kc = (c2 & 3) * 8;
        gload_lds16(Bh + (size_t)(n0 + row) * ISZ + ke + kc, S + 16384 + c2 * 16);
      } else {                 // Blo
        int c2 = c - 1280; int row = c2 >> 2, kc = (c2 & 3) * 8;
        gload_lds16(Bl + (size_t)(n0 + row) * ISZ + ke + kc, S + 20480 + c2 * 16);
      }
    }
  };
  stage(0, 0);
  __syncthreads();

  for (int kk = 0; kk < 32; ++kk) {
    const int cur = kk & 1;
    if (kk < 31) stage(cur ^ 1, kk + 1);
    const char* S = smem + cur * 24576;
    const int fo = (lane & 15) * 64 + (lane >> 4) * 16;
    f16x8 ah[4], al[4], bh[2], bl[2];
#pragma unroll
    for (int mt = 0; mt < 4; ++mt) {
      ah[mt] = *(const f16x8*)(S + (wm + mt * 16) * 64 + fo);
      al[mt] = *(const f16x8*)(S + 8192 + (wm + mt * 16) * 64 + fo);
    }
#pragma unroll
    for (int nt = 0; nt < 2; ++nt) {
      bh[nt] = *(const f16x8*)(S + 16384 + (wn + nt * 16) * 64 + fo);
      bl[nt] = *(const f16x8*)(S + 20480 + (wn + nt * 16) * 64 + fo);
    }
#pragma unroll
    for (int mt = 0; mt < 4; ++mt)
#pragma unroll
      for (int nt = 0; nt < 2; ++nt) {
        ach[mt][nt] = __builtin_amdgcn_mfma_f32_16x16x32_f16(ah[mt], bh[nt], ach[mt][nt], 0, 0, 0);
        acl[mt][nt] = __builtin_amdgcn_mfma_f32_16x16x32_f16(al[mt], bh[nt], acl[mt][nt], 0, 0, 0);
        acl[mt][nt] = __builtin_amdgcn_mfma_f32_16x16x32_f16(ah[mt], bl[nt], acl[mt][nt], 0, 0, 0);
      }
    __syncthreads();
  }

  // epilogue: fp32 C = hi + lo/2048
#pragma unroll
  for (int mt = 0; mt < 4; ++mt)
#pragma unroll
    for (int nt = 0; nt < 2; ++nt)
#pragma unroll
      for (int r = 0; r < 4; ++r)
        C[(size_t)(m0 + wm + mt * 16 + (lane >> 4) * 4 + r) * GSZ + n0 + wn + nt * 16 + (lane & 15)] =
            ach[mt][nt][r] + acl[mt][nt][r] * (1.0f / 2048.0f);
}

// ---------------- persistent recurrent kernel (one time chunk) ----------------
// 128 wgs x 256 thr. wg owns 8 h-cols -> 32 gate-cols; W_hh hi+lo slices in LDS
// (128 KiB, XOR-swizzled). One device-scope grid barrier per step; h split
// hi/lo double-buffered in global.
__global__ __launch_bounds__(256, 1) void k_lstm(
    const _Float16* __restrict__ Whh_hi, const _Float16* __restrict__ Whh_lo,
    const float* __restrict__ Gx, const float* __restrict__ bsum,
    const float* __restrict__ cand, _Float16* __restrict__ hhi,
    _Float16* __restrict__ hlo, float* __restrict__ cstate,
    float* __restrict__ out, unsigned int* __restrict__ bar, int t0) {
  __shared__ char Wlds[131072];   // hi 64K | lo 64K : [32 gcol][1024 k] f16, swizzled
  __shared__ float gbuf[64 * 36]; // [64 b][32 gcol], stride 36
  const int tid = threadIdx.x, lane = tid & 63, w = tid >> 6, wg = blockIdx.x;
  const int col0 = wg * 8;

  // stage W slices once: 8192 chunks of 16B via regs (dest swizzled)
#pragma unroll
  for (int i = 0; i < 32; ++i) {
    int c = i * 256 + tid;
    int p = c >> 12, cc = c & 4095;           // plane, chunk-in-plane
    int gcol = cc >> 7, kc = cc & 127;        // gcol = g*8+j
    int n = (gcol >> 3) * 1024 + col0 + (gcol & 7);
    const _Float16* Wsrc = p ? Whh_lo : Whh_hi;
    uint4 v = *(const uint4*)(Wsrc + (size_t)n * HSZ + kc * 8);
    *(uint4*)(Wlds + p * 65536 + gcol * 2048 + ((kc * 16) ^ ((gcol & 7) << 4))) = v;
  }

  const int pb = tid >> 2, pj0 = (tid & 3) * 2;
  const float* csrc = (t0 == 0) ? (cand + (size_t)pb * HSZ + col0 + pj0)
                                : (cstate + (size_t)pb * HSZ + col0 + pj0);
  float2 c2v = *(const float2*)csrc;
  float brv[4][2];
#pragma unroll
  for (int g = 0; g < 4; ++g) {
    brv[g][0] = bsum[g * 1024 + col0 + pj0];
    brv[g][1] = bsum[g * 1024 + col0 + pj0 + 1];
  }
  __syncthreads();

  const int arow = w * 16 + (lane & 15);
  const int kq = (lane >> 4) * 8;
  const int gc = lane & 15;
  const int bxor = (gc & 7) << 4;
  float2 h2v = (float2){0.f, 0.f};

  for (int ts = 0; ts < TC; ++ts) {
    const int t = t0 + ts;
    const int par = t & 1;
    const _Float16* ha = hhi + (size_t)par * BH;
    const _Float16* la = hlo + (size_t)par * BH;

    // prefetch this step's Gx (fp32): 4 gates x 2 cols
    float2 gx[4];
    {
      const float* gp = Gx + ((size_t)ts * BATCH + pb) * GSZ + col0 + pj0;
#pragma unroll
      for (int g = 0; g < 4; ++g) gx[g] = *(const float2*)(gp + g * 1024);
    }

    f32x4 ahc[2], alc[2];
    ahc[0] = ahc[1] = alc[0] = alc[1] = (f32x4){0.f, 0.f, 0.f, 0.f};
#pragma unroll
    for (int kk = 0; kk < 32; ++kk) {
      const int k = kk * 32 + kq;
      f16x8 av = *(const f16x8*)(ha + (size_t)arow * HSZ + k);
      f16x8 lv = *(const f16x8*)(la + (size_t)arow * HSZ + k);
#pragma unroll
      for (int nt = 0; nt < 2; ++nt) {
        const char* base = Wlds + (nt * 16 + gc) * 2048;
        f16x8 bh = *(const f16x8*)(base + ((k * 2) ^ bxor));
        f16x8 bl = *(const f16x8*)(base + 65536 + ((k * 2) ^ bxor));
        ahc[nt] = __builtin_amdgcn_mfma_f32_16x16x32_f16(av, bh, ahc[nt], 0, 0, 0);
        alc[nt] = __builtin_amdgcn_mfma_f32_16x16x32_f16(lv, bh, alc[nt], 0, 0, 0);
        alc[nt] = __builtin_amdgcn_mfma_f32_16x16x32_f16(av, bl, alc[nt], 0, 0, 0);
      }
    }
#pragma unroll
    for (int nt = 0; nt < 2; ++nt)
#pragma unroll
      for (int r = 0; r < 4; ++r)
        gbuf[(w * 16 + (lane >> 4) * 4 + r) * 36 + nt * 16 + gc] =
            ahc[nt][r] + alc[nt][r] * (1.0f / 2048.0f);
    __syncthreads();

    {  // fused pointwise: gates = Hh(gbuf) + Gx + b ; gbuf col = g*8+j
      f16x2 hh2, hl2;
#pragma unroll
      for (int e = 0; e < 2; ++e) {
        int j = pj0 + e;
        float vi = gbuf[pb * 36 + 0 + j]  + ((e == 0) ? gx[0].x : gx[0].y) + brv[0][e];
        float vf = gbuf[pb * 36 + 8 + j]  + ((e == 0) ? gx[1].x : gx[1].y) + brv[1][e];
        float vg = gbuf[pb * 36 + 16 + j] + ((e == 0) ? gx[2].x : gx[2].y) + brv[2][e];
        float vo = gbuf[pb * 36 + 24 + j] + ((e == 0) ? gx[3].x : gx[3].y) + brv[3][e];
        float cc = (e == 0) ? c2v.x : c2v.y;
        float cn = sigf(vf) * cc + sigf(vi) * tanhf(vg);
        float hv = sigf(vo) * tanhf(cn);
        if (e == 0) { c2v.x = cn; h2v.x = hv; } else { c2v.y = cn; h2v.y = hv; }
        _Float16 hhh = (_Float16)hv;
        hh2[e] = hhh;
        hl2[e] = (_Float16)((hv - (float)hhh) * 2048.0f);
      }
      *(float2*)&out[(size_t)t * BH + (size_t)pb * HSZ + col0 + pj0] = h2v;
      *(f16x2*)&hhi[(size_t)(1 - par) * BH + (size_t)pb * HSZ + col0 + pj0] = hh2;
      *(f16x2*)&hlo[(size_t)(1 - par) * BH + (size_t)pb * HSZ + col0 + pj0] = hl2;
      if (t == T_STEPS - 1) {
        *(float2*)&out[(size_t)TBH + (size_t)pb * HSZ + col0 + pj0] = h2v;
        *(float2*)&out[(size_t)TBH + BH + (size_t)pb * HSZ + col0 + pj0] = c2v;
      }
      if (ts == TC - 1)
        *(float2*)&cstate[(size_t)pb * HSZ + col0 + pj0] = c2v;
    }

    // device-scope grid barrier (round-0-proven constructs only)
    __syncthreads();
    if (tid == 0) {
      __threadfence();
      unsigned int v = __hip_atomic_fetch_add(&bar[0], 1u, __ATOMIC_ACQ_REL,
                                              __HIP_MEMORY_SCOPE_AGENT);
      if (v == (unsigned int)(NWG - 1)) {
        __hip_atomic_store(&bar[0], 0u, __ATOMIC_RELAXED, __HIP_MEMORY_SCOPE_AGENT);
        __hip_atomic_store(&bar[1], (unsigned int)(t + 1), __ATOMIC_RELEASE,
                           __HIP_MEMORY_SCOPE_AGENT);
      } else {
        while (__hip_atomic_load(&bar[1], __ATOMIC_ACQUIRE, __HIP_MEMORY_SCOPE_AGENT) <
               (unsigned int)(t + 1)) {
          __builtin_amdgcn_s_sleep(2);
        }
      }
      __threadfence();
    }
    __syncthreads();
  }
}

extern "C" void kernel_launch(void* const* d_in, const int* in_sizes, int n_in,
                              void* d_out, int out_size, void* d_ws, size_t ws_size,
                              hipStream_t stream) {
  const float* x      = (const float*)d_in[0];
  const float* hidden = (const float*)d_in[1];
  const float* cand   = (const float*)d_in[2];
  const float* w_ih   = (const float*)d_in[3];
  const float* w_hh   = (const float*)d_in[4];
  const float* b_ih   = (const float*)d_in[5];
  const float* b_hh   = (const float*)d_in[6];
  const int*   biasf  = (const int*)d_in[7];
  float* out = (float*)d_out;

  char* ws = (char*)d_ws;
  // ws layout (bytes), total 168,575,232 (~161 MB)
  _Float16* Xhi   = (_Float16*)(ws + 0);           // 33,554,432
  _Float16* Xlo   = (_Float16*)(ws + 33554432);    // 33,554,432
  _Float16* Wihh  = (_Float16*)(ws + 67108864);    //  8,388,608
  _Float16* Wihl  = (_Float16*)(ws + 75497472);    //  8,388,608
  _Float16* Whhh  = (_Float16*)(ws + 83886080);    //  8,388,608
  _Float16* Whhl  = (_Float16*)(ws + 92274688);    //  8,388,608
  float*    Gx    = (float*)(ws + 100663296);      // 67,108,864 (one chunk)
  float*    bsum  = (float*)(ws + 167772160);      //     16,384
  _Float16* hhi   = (_Float16*)(ws + 167788544);   //    262,144 (2 buffers)
  _Float16* hlo   = (_Float16*)(ws + 168050688);   //    262,144
  float*    cstate= (float*)(ws + 168312832);      //    262,144
  unsigned int* bar = (unsigned int*)(ws + 168574976); // 256

  if (ws_size < (size_t)168575232) return;  // distinct failure signature (out stays 0)

  k_split<<<2048, 256, 0, stream>>>(x, Xhi, Xlo, (T_STEPS * BATCH * ISZ) / 4);
  k_split<<<1024, 256, 0, stream>>>(w_ih, Wihh, Wihl, (GSZ * ISZ) / 4);
  k_split<<<1024, 256, 0, stream>>>(w_hh, Whhh, Whhl, (GSZ * HSZ) / 4);
  k_init<<<64, 256, 0, stream>>>(b_ih, b_hh, biasf, hidden, bsum, hhi, hlo, bar);

  for (int c = 0; c < NCHUNK; ++c) {
    dim3 gg(GSZ / 64, (TC * BATCH) / 128);  // (64, 32)
    k_gemm_gx<<<gg, 256, 0, stream>>>(Xhi, Xlo, Wihh, Wihl, Gx, c * TC * BATCH);
    k_lstm<<<NWG, 256, 0, stream>>>(Whhh, Whhl, Gx, bsum, cand, hhi, hlo, cstate,
                                    out, bar, c * TC);
  }
}